// Round 1
// baseline (602.038 us; speedup 1.0000x reference)
//
#include <hip/hip_runtime.h>
#include <math.h>

#define BATCH 8
#define C 64
#define NH 8
#define HD 8
#define LTXT 77
#define H0 64
#define W0 64
#define HW0 (H0*W0)

typedef __attribute__((ext_vector_type(8))) short bfrag;    // 8 bf16 (4 VGPR)
typedef __attribute__((ext_vector_type(4))) float ffrag;    // 4 fp32 acc
typedef __attribute__((ext_vector_type(8))) unsigned short us8;
typedef __attribute__((ext_vector_type(4))) unsigned short us4;

__device__ __forceinline__ unsigned short f2bf(float f) {
    unsigned u = __builtin_bit_cast(unsigned, f);
    u += 0x7fff + ((u >> 16) & 1);   // RNE
    return (unsigned short)(u >> 16);
}

// ---------------- text projection: tf[b,l,c] = th[b,l,:] . proj_w[c,:] + proj_b[c]
__global__ void text_proj_kernel(const float* __restrict__ th, const float* __restrict__ pw,
                                 const float* __restrict__ pb, float* __restrict__ tf) {
    __shared__ float sh[512];
    int bl = blockIdx.x;
    int c = threadIdx.x;
    const float* row = th + (size_t)bl * 512;
    for (int i = c; i < 512; i += 64) sh[i] = row[i];
    __syncthreads();
    const float* wrow = pw + c * 512;
    float acc = pb[c];
    for (int i = 0; i < 512; i += 4) {
        acc += sh[i] * wrow[i] + sh[i+1] * wrow[i+1] + sh[i+2] * wrow[i+2] + sh[i+3] * wrow[i+3];
    }
    tf[bl * 64 + c] = acc;
}

// ---------------- merged prep: conv_in (blocks 0..8191) + pack_up (8192..9343)
// + pack_final (9344..9379) + pack_proj (9380..9635)
__global__ void __launch_bounds__(256)
prep_kernel(const float* __restrict__ x, const float* __restrict__ cf_w,
            const float* __restrict__ cf_b, float* __restrict__ feat,
            const float* __restrict__ up_w,
            unsigned short* __restrict__ PW1, unsigned short* __restrict__ PW2,
            const float* __restrict__ cl_w, unsigned short* __restrict__ PWF,
            const float* __restrict__ qw, const float* __restrict__ ow,
            unsigned short* __restrict__ PQ, unsigned short* __restrict__ PO) {
    int blk = blockIdx.x;
    if (blk < 8192) {
        // conv_in: x[8,3,64,64] -> feat[8,64,64,64] fp32 NCHW
        int idx = blk * 256 + threadIdx.x;
        int wx = idx & 63;
        int h = (idx >> 6) & 63;
        int o = (idx >> 12) & 63;
        int b = idx >> 18;
        const float* wr = cf_w + o * 27;
        float acc = cf_b[o];
        for (int ci = 0; ci < 3; ci++) {
            for (int ky = 0; ky < 3; ky++) {
                int y = h + ky - 1;
                if ((unsigned)y >= 64u) continue;
                const float* xr = x + (((size_t)b * 3 + ci) * 64 + y) * 64;
                const float* wk = wr + ci * 9 + ky * 3;
                if (wx > 0) acc += xr[wx - 1] * wk[0];
                acc += xr[wx] * wk[1];
                if (wx < 63) acc += xr[wx + 1] * wk[2];
            }
        }
        feat[idx] = acc;
    } else if (blk < 8192 + 1152) {
        int e0 = blk - 8192;
        int st = e0 / 576;
        int e = (e0 % 576) * 256 + threadIdx.x;   // < 147456
        const float* w = up_w + (size_t)st * 147456;
        unsigned short* d = st ? PW2 : PW1;
        int j = e & 7, n = (e >> 3) & 255, q = (e >> 11) & 3, s = (e >> 13) & 1, t = e >> 14;
        int c = n & 63, g = n >> 6;
        int co = 4 * c + g, ci = 32 * s + 8 * q + j;
        d[e] = f2bf(w[co * 576 + ci * 9 + t]);
    } else if (blk < 8192 + 1152 + 36) {
        int e = (blk - 8192 - 1152) * 256 + threadIdx.x;   // < 9216
        int j = e & 7, n = (e >> 3) & 15, q = (e >> 7) & 3, s = (e >> 9) & 1, t = e >> 10;
        int ci = 32 * s + 8 * q + j;
        float v = (n < 3) ? cl_w[n * 576 + ci * 9 + t] : 0.f;
        PWF[e] = f2bf(v);
    } else {
        int e = (blk - 8192 - 1152 - 36) * 256 + threadIdx.x;   // < 65536
        int j = e & 7, n = (e >> 3) & 63, quad = (e >> 9) & 3, kt = (e >> 11) & 1, layer = e >> 12;
        int c = kt * 32 + quad * 8 + j;
        PQ[e] = f2bf(qw[layer * 4096 + n * 64 + c]);
        PO[e] = f2bf(ow[layer * 4096 + n * 64 + c]);
    }
}

// ---------------- K/V for ALL 16 blocks upfront, emitted in bf16 MFMA-ready layouts:
// k16[lb][t(80)][c(64)]   (A-frag rows = tokens; scale*log2e folded; t>=77 zero)
// vt16[lb][c(64)][t(96)]  (A-frag rows = channels, token-contiguous; t>=77 zero)
__global__ void kv_all_kernel(const float* __restrict__ tf,
                              const float* __restrict__ kw, const float* __restrict__ kb,
                              const float* __restrict__ vw, const float* __restrict__ vb,
                              const float* __restrict__ l2w, const float* __restrict__ l2b,
                              unsigned short* __restrict__ k16, unsigned short* __restrict__ vt16) {
    __shared__ float sh[64];
    int g = blockIdx.x;
    int t = g % 96;
    int lb = g / 96;          // layer*8 + b
    int b = lb & 7;
    int blk = lb >> 3;
    int o = threadIdx.x;
    if (t >= LTXT) {
        if (t < 80) k16[((size_t)lb * 80 + t) * 64 + o] = 0;
        vt16[((size_t)lb * 64 + o) * 96 + t] = 0;
        return;
    }
    sh[o] = tf[(b * LTXT + t) * 64 + o];
    __syncthreads();
    const float* krw = kw + blk * 4096 + o * 64;
    const float* vrw = vw + blk * 4096 + o * 64;
    float ka = kb[blk * 64 + o], va = vb[blk * 64 + o];
    for (int c2 = 0; c2 < 64; c2++) {
        float tv = sh[c2];
        ka += tv * krw[c2];
        va += tv * vrw[c2];
    }
    float s = ka;
    for (int off = 32; off; off >>= 1) s += __shfl_xor(s, off, 64);
    float mean = s * (1.0f / 64.0f);
    float d = ka - mean;
    float s2 = d * d;
    for (int off = 32; off; off >>= 1) s2 += __shfl_xor(s2, off, 64);
    float rstd = rsqrtf(s2 * (1.0f / 64.0f) + 1e-5f);
    float kn = (d * rstd * l2w[blk * 64 + o] + l2b[blk * 64 + o]) * 0.51006973f;
    k16[((size_t)lb * 80 + t) * 64 + o] = f2bf(kn);
    vt16[((size_t)lb * 64 + o) * 96 + t] = f2bf(va);
}

// ---------------- ALL 16 attention blocks fused, 1024 threads = 16 waves.
// NEW: QK^T and P.V on MFMA (matrix pipe was at 1.2% util while VALU sat at 57%).
// Per layer: q-proj GEMM (raw q kept in regs) -> LN stats -> per-lane normalize ->
// 4 passes x 2 heads: S^T = mfma(K, qn) ; exp2 + mask -> bf16 P in LDS ;
// denominators via shfl ; O^T = mfma(V^T, P^T) -> sob. Only exp2 stays on VALU.
__global__ void __launch_bounds__(1024, 8)
attn_all_kernel(const float* __restrict__ feat,
                const unsigned short* __restrict__ k16, const unsigned short* __restrict__ vt16,
                const unsigned short* __restrict__ PQ, const unsigned short* __restrict__ PO,
                const float* __restrict__ qb_a, const float* __restrict__ ob_a,
                const float* __restrict__ l1w_a, const float* __restrict__ l1b_a,
                unsigned short* __restrict__ X1) {
    __shared__ __attribute__((aligned(16))) unsigned short sfb[64][72]; // residual bf16 [p][c]
    __shared__ __attribute__((aligned(16))) unsigned short sob[64][72]; // attn-out bf16 [p][c]
    __shared__ __attribute__((aligned(16))) unsigned short qn[64][72];  // normalized q bf16 [p][c]
    __shared__ __attribute__((aligned(16))) float red[2][4][64];        // LN partials [s][nt][p]
    __shared__ float dpart[2][8][16];                                   // denom partials [ms][h1*4+ntp][px]
    // p16 (bf16 P, 2 heads x 64 px x 104 tok) aliases out-proj fp32 scratch qf[64][68]
    __shared__ __attribute__((aligned(16))) char upool[2 * 64 * 104 * 2]; // 26624 B

    unsigned short (*P16)[64][104] = (unsigned short (*)[64][104])upool;
    float (*qf)[68] = (float (*)[68])upool;

    int b = blockIdx.x >> 6;
    int tile = blockIdx.x & 63;
    int n0 = tile << 6;
    int wv = __builtin_amdgcn_readfirstlane(threadIdx.x >> 6);  // wave 0..15
    int lane = threadIdx.x & 63;
    int p = lane;
    int quad = lane >> 4, n16 = lane & 15;
    int mt = wv >> 2, nt = wv & 3;      // GEMM C-tile role
    int o0 = wv * 4;                    // ownership role: channels o0..o0+3, pixel p
    int cch = nt * 16 + n16;            // GEMM output channel
    int p0 = mt * 16 + quad * 4;        // GEMM output pixel base
    int h1 = wv >> 3, ntp = (wv >> 1) & 3, ms = wv & 1;   // attention pass roles
    int pxl = ntp * 16 + n16;           // attention pixel col
    const float* fbase = feat + ((size_t)b << 18) + n0;

    // stage: residual regs + bf16 mirror
    float rres[4];
#pragma unroll
    for (int j = 0; j < 4; j++) rres[j] = fbase[(o0 + j) * HW0 + p];
    {
        us4 v;
#pragma unroll
        for (int j = 0; j < 4; j++) v[j] = f2bf(rres[j]);
        *(us4*)&sfb[p][o0] = v;
    }

    const float pxk = 0.05f / 63.0f;
    float py005 = (float)tile * pxk;
    const bfrag zb = (bfrag)(short)0;
    __syncthreads();

#pragma unroll 1
    for (int layer = 0; layer < 16; layer++) {
        const float* qb = qb_a + layer * 64;
        const float* ob = ob_a + layer * 64;
        const float* l1w = l1w_a + layer * 64;
        const float* l1b = l1b_a + layer * 64;
        size_t kvbase = (size_t)layer * BATCH + b;

        // ---- A: q-proj GEMM; raw q kept in regs; LN partials via in-wave reduction
        float ov[4];
        {
            bfrag af0 = *(const bfrag*)&sfb[mt * 16 + n16][quad * 8];
            bfrag af1 = *(const bfrag*)&sfb[mt * 16 + n16][32 + quad * 8];
            const unsigned short* bqp = PQ + layer * 4096 + (size_t)((quad * 64) + nt * 16 + n16) * 8;
            bfrag bf0 = *(const bfrag*)bqp;
            bfrag bf1 = *(const bfrag*)(bqp + 2048);   // kt=1 chunk
            ffrag cc = (ffrag)0.f;
            cc = __builtin_amdgcn_mfma_f32_16x16x32_bf16(af0, bf0, cc, 0, 0, 0);
            cc = __builtin_amdgcn_mfma_f32_16x16x32_bf16(af1, bf1, cc, 0, 0, 0);
            float qbv = qb[cch];
            float pe0 = (nt < 2) ? (float)p0 * pxk : py005;
            float ped = (nt < 2) ? pxk : 0.f;
            ov[0] = cc[0] + qbv + pe0;
            ov[1] = cc[1] + qbv + pe0 + ped;
            ov[2] = cc[2] + qbv + pe0 + 2.f * ped;
            ov[3] = cc[3] + qbv + pe0 + 3.f * ped;

            // channel-sum over the 16 n16 lanes (same quad), per pixel r
            float sv[4], sq[4];
#pragma unroll
            for (int r = 0; r < 4; r++) {
                float s = ov[r], s2v = ov[r] * ov[r];
                s += __shfl_xor(s, 1);  s2v += __shfl_xor(s2v, 1);
                s += __shfl_xor(s, 2);  s2v += __shfl_xor(s2v, 2);
                s += __shfl_xor(s, 4);  s2v += __shfl_xor(s2v, 4);
                s += __shfl_xor(s, 8);  s2v += __shfl_xor(s2v, 8);
                sv[r] = s; sq[r] = s2v;
            }
            if (n16 == 0) {
                *(float4*)&red[0][nt][p0] = (float4){sv[0], sv[1], sv[2], sv[3]};
                *(float4*)&red[1][nt][p0] = (float4){sq[0], sq[1], sq[2], sq[3]};
            }
        }
        __syncthreads();   // B1: red complete

        // ---- A2: per-lane LN normalize of own raw q -> qn bf16 [p][c]
        {
            ffrag ts = (ffrag)0.f, tq = (ffrag)0.f;
#pragma unroll
            for (int g4 = 0; g4 < 4; g4++) {
                ts += *(const ffrag*)&red[0][g4][p0];
                tq += *(const ffrag*)&red[1][g4][p0];
            }
            float wch = l1w[cch], bch = l1b[cch];
#pragma unroll
            for (int r = 0; r < 4; r++) {
                float mean = ts[r] * (1.0f / 64.0f);
                float var = tq[r] * (1.0f / 64.0f) - mean * mean;
                float rstd = rsqrtf(var + 1e-5f);
                qn[p0 + r][cch] = f2bf((ov[r] - mean) * rstd * wch + bch);
            }
        }
        __syncthreads();   // B2: qn ready

        // ---- C: attention, 4 passes of 2 heads (LDS-bounded)
#pragma unroll 1
        for (int pass = 0; pass < 4; pass++) {
            int h = pass * 2 + h1;
            // --- S^T = mfma(K_tokens, qn), exp2+mask, bf16 -> P16
            {
                bfrag bq = zb;
                if (quad == 0) bq = *(const bfrag*)&qn[pxl][h * 8];
                const unsigned short* kr = k16 + kvbase * (80 * 64) + h * 8;
                float dsum = 0.f;

#define S_MT(mtc) { \
    bfrag ak = zb; \
    if (quad == 0) ak = *(const bfrag*)(kr + ((mtc) * 16 + n16) * 64); \
    ffrag cc = (ffrag)0.f; \
    cc = __builtin_amdgcn_mfma_f32_16x16x32_bf16(ak, bq, cc, 0, 0, 0); \
    float e0 = exp2f(cc[0]), e1 = exp2f(cc[1]), e2 = exp2f(cc[2]), e3 = exp2f(cc[3]); \
    if ((mtc) == 4) { \
        int tb = 64 + quad * 4; \
        if (tb + 0 >= 77) e0 = 0.f; \
        if (tb + 1 >= 77) e1 = 0.f; \
        if (tb + 2 >= 77) e2 = 0.f; \
        if (tb + 3 >= 77) e3 = 0.f; \
    } \
    dsum += (e0 + e1) + (e2 + e3); \
    unsigned long long pw = (unsigned long long)((unsigned)f2bf(e0) | ((unsigned)f2bf(e1) << 16)) \
                          | ((unsigned long long)((unsigned)f2bf(e2) | ((unsigned)f2bf(e3) << 16)) << 32); \
    *(unsigned long long*)&P16[h1][pxl][(mtc) * 16 + quad * 4] = pw; \
}
                if (ms == 0) {
                    S_MT(0); S_MT(1); S_MT(2);
                } else {
                    S_MT(3); S_MT(4);
                    // zero pad tokens 80..95 (kk=2 chunk tail)
                    *(unsigned long long*)&P16[h1][pxl][80 + quad * 4] = 0ull;
                }
#undef S_MT
                dsum += __shfl_xor(dsum, 16, 64);
                dsum += __shfl_xor(dsum, 32, 64);
                if (quad == 0) dpart[ms][h1 * 4 + ntp][n16] = dsum;
            }
            __syncthreads();   // P + denom partials ready

            // --- O^T = mfma(V^T, P^T), scale by 1/den -> sob
            if (ms == 0) {
                float den = dpart[0][h1 * 4 + ntp][n16] + dpart[1][h1 * 4 + ntp][n16];
                float inv = 1.0f / den;
                const unsigned short* vr = vt16 + (kvbase * 64 + h * 8 + n16) * 96;
                ffrag acc = (ffrag)0.f;
#pragma unroll
                for (int kk = 0; kk < 3; kk++) {
                    bfrag av = zb;
                    if (n16 < 8) av = *(const bfrag*)(vr + kk * 32 + quad * 8);
                    bfrag bp = *(const bfrag*)&P16[h1][pxl][kk * 32 + quad * 8];
                    acc = __builtin_amdgcn_mfma_f32_16x16x32_bf16(av, bp, acc, 0, 0, 0);
                }
                if (quad < 2) {
                    us4 v4;
#pragma unroll
                    for (int r = 0; r < 4; r++) v4[r] = f2bf(acc[r] * inv);
                    *(us4*)&sob[pxl][h * 8 + quad * 4] = v4;
                }
            }
            __syncthreads();   // P16 consumed; sob slice ready
        }

        // ---- D: out-proj GEMM (A from sob), result -> qf (aliases P16, now dead)
        {
            bfrag af0 = *(const bfrag*)&sob[mt * 16 + n16][quad * 8];
            bfrag af1 = *(const bfrag*)&sob[mt * 16 + n16][32 + quad * 8];
            const unsigned short* bo = PO + layer * 4096 + (size_t)((quad * 64) + nt * 16 + n16) * 8;
            bfrag bf0 = *(const bfrag*)bo;
            bfrag bf1 = *(const bfrag*)(bo + 2048);
            ffrag cc = (ffrag)0.f;
            cc = __builtin_amdgcn_mfma_f32_16x16x32_bf16(af0, bf0, cc, 0, 0, 0);
            cc = __builtin_amdgcn_mfma_f32_16x16x32_bf16(af1, bf1, cc, 0, 0, 0);
            float obv = ob[cch];
            float4 o4;
            o4.x = cc[0] + obv; o4.y = cc[1] + obv; o4.z = cc[2] + obv; o4.w = cc[3] + obv;
            *(float4*)&qf[cch][p0] = o4;
        }
        __syncthreads();   // B6

        // ---- E: residual update in regs + refresh bf16 mirror
        {
            us4 v;
#pragma unroll
            for (int j = 0; j < 4; j++) {
                rres[j] += qf[o0 + j][p];
                v[j] = f2bf(rres[j]);
            }
            *(us4*)&sfb[p][o0] = v;
        }
        __syncthreads();   // B7
    }

    // final write: NHWC bf16
    us4 v;
#pragma unroll
    for (int j = 0; j < 4; j++) v[j] = f2bf(rres[j]);
    *(us4*)(X1 + ((size_t)(b * 4096 + n0 + p)) * 64 + o0) = v;
}

// ---------------- upsample conv as 9-tap implicit GEMM, MFMA 16x16x32 bf16
// LDS-staged input rows; co-split x2 via blockIdx.y (n'-half) for occupancy.
__global__ void __launch_bounds__(256)
upconv_mfma_kernel(const unsigned short* __restrict__ X, const unsigned short* __restrict__ Bp,
                   const float* __restrict__ bias, unsigned short* __restrict__ Y,
                   int Hin, int Win) {
    __shared__ __attribute__((aligned(16))) unsigned short sx[3 * 66 * 72];  // 28.5 KB

    int y = blockIdx.y;                 // n'-half (r1 = y)
    int wv = threadIdx.x >> 6;
    int lane = threadIdx.x & 63;
    int q = lane >> 4, n16 = lane & 15;
    int m0 = blockIdx.x * 64;
    int hw = Hin * Win;
    int b = m0 / hw, rem = m0 % hw;
    int h = rem / Win, w0 = rem % Win;
    const unsigned short* Xb = X + (size_t)b * hw * 64;

    // stage 3 rows x 66 px x 64 ch (zero halo), ch-padded to 72
    const us8 z8 = (us8)(unsigned short)0;
    for (int e = threadIdx.x; e < 1584; e += 256) {
        int ch8 = e & 7;
        int pxi = (e >> 3) % 66;
        int row = e / 528;
        int hh = h + row - 1, wp = w0 + pxi - 1;
        us8 v = z8;
        if ((unsigned)hh < (unsigned)Hin && (unsigned)wp < (unsigned)Win)
            v = *(const us8*)(Xb + ((size_t)hh * Win + wp) * 64 + ch8 * 8);
        *(us8*)&sx[row * 4752 + pxi * 72 + ch8 * 8] = v;
    }
    __syncthreads();

    ffrag acc[4][2];
#pragma unroll
    for (int i = 0; i < 4; i++)
#pragma unroll
        for (int j2 = 0; j2 < 2; j2++) acc[i][j2] = (ffrag)0.f;

    int npb = y * 128 + wv * 32;   // n' base for this wave

    for (int t = 0; t < 9; t++) {
        int dy = t / 3, dx = t % 3;
        bfrag af[4][2];
#pragma unroll
        for (int mt = 0; mt < 4; mt++) {
            const unsigned short* sp = &sx[dy * 4752 + (mt * 16 + n16 + dx) * 72 + q * 8];
            af[mt][0] = *(const bfrag*)sp;
            af[mt][1] = *(const bfrag*)(sp + 32);
        }
#pragma unroll
        for (int s = 0; s < 2; s++) {
#pragma unroll
            for (int nt = 0; nt < 2; nt++) {
                bfrag bf = *(const bfrag*)(Bp + (size_t)((((t * 2 + s) * 4 + q) * 256) + npb + nt * 16 + n16) * 8);
#pragma unroll
                for (int mt = 0; mt < 4; mt++)
                    acc[mt][nt] = __builtin_amdgcn_mfma_f32_16x16x32_bf16(af[mt][s], bf, acc[mt][nt], 0, 0, 0);
            }
        }
    }

    int g = y * 2 + (wv >> 1);         // g' = 2*r1 + r2
    int r1 = y, r2 = wv >> 1;
    int cbase = (wv & 1) * 32;
    float bv[2];
#pragma unroll
    for (int nt = 0; nt < 2; nt++) bv[nt] = bias[4 * (cbase + nt * 16 + n16) + g];
    int Wo = Win * 2;
    unsigned short* Yb = Y + ((size_t)b * Hin * 2 * Wo + (size_t)(2 * h + r1) * Wo + r2) * 64;
#pragma unroll
    for (int mt = 0; mt < 4; mt++) {
#pragma unroll
        for (int r = 0; r < 4; r++) {
            int m = mt * 16 + q * 4 + r;   // C/D: row = quad*4 + reg
            unsigned short* dst = Yb + (size_t)(2 * (w0 + m)) * 64;
#pragma unroll
            for (int nt = 0; nt < 2; nt++) {
                float v = acc[mt][nt][r] + bv[nt];
                v = fmaxf(v, 0.f);
                dst[cbase + nt * 16 + n16] = f2bf(v);
            }
        }
    }
}

// ---------------- final conv as 9-tap implicit GEMM, N=16 (3 real), fp32 NCHW out
// 2D tile: 64 px x 4 rows per block; 6 rows x 66 px staged in LDS (57 KB).
__global__ void __launch_bounds__(256)
final_mfma_kernel(const unsigned short* __restrict__ X, const unsigned short* __restrict__ Bp,
                  const float* __restrict__ bias, float* __restrict__ out) {
    __shared__ __attribute__((aligned(16))) unsigned short sx[6 * 66 * 72];  // 57 KB

    int t0 = blockIdx.x;
    int wseg = t0 & 3;
    int rg = (t0 >> 2) & 63;
    int b = t0 >> 8;
    int y0 = rg * 4, w0 = wseg * 64;
    int wv = threadIdx.x >> 6, lane = threadIdx.x & 63;
    int q = lane >> 4, n16 = lane & 15;
    const unsigned short* Xb = X + (size_t)b * 65536 * 64;

    // stage 6 rows x 66 px x 64 ch (zero halo), ch pitch 72
    const us8 z8 = (us8)(unsigned short)0;
    for (int e = threadIdx.x; e < 3168; e += 256) {
        int ch8 = e & 7;
        int pxi = (e >> 3) % 66;
        int row = e / 528;
        int hh = y0 - 1 + row, wp = w0 - 1 + pxi;
        us8 v = z8;
        if ((unsigned)hh < 256u && (unsigned)wp < 256u)
            v = *(const us8*)(Xb + ((size_t)hh * 256 + wp) * 64 + ch8 * 8);
        *(us8*)&sx[row * 4752 + pxi * 72 + ch8 * 8] = v;
    }
    __syncthreads();

    // wave wv handles row y0+wv, 64 px
    ffrag acc[4];
#pragma unroll
    for (int i = 0; i < 4; i++) acc[i] = (ffrag)0.f;

    for (int t = 0; t < 9; t++) {
        int dy = t / 3, dx = t % 3;
        bfrag af[4][2];
#pragma unroll
        for (int mt = 0; mt < 4; mt++) {
            const unsigned short* sp = &sx[(wv + dy) * 4752 + (mt * 16 + n16 + dx) * 72 + q * 8];
            af[mt][0] = *(const bfrag*)sp;
            af[mt][1] = *(const bfrag*)(sp + 32);
        }
#pragma unroll
        for (int s = 0; s < 2; s++) {
            bfrag bf = *(const bfrag*)(Bp + (size_t)((((t * 2 + s) * 4 + q) * 16) + n16) * 8);
#pragma unroll
            for (int mt = 0; mt < 4; mt++)
                acc[mt] = __builtin_amdgcn_mfma_f32_16x16x32_bf16(af[mt][s], bf, acc[mt], 0, 0, 0);
        }
    }

    if (n16 < 3) {
        float bj = bias[n16];
        float* ob = out + (((size_t)b * 3 + n16) * 256 + (y0 + wv)) * 256;
#pragma unroll
        for (int mt = 0; mt < 4; mt++)
#pragma unroll
            for (int r = 0; r < 4; r++)
                ob[w0 + mt * 16 + q * 4 + r] = acc[mt][r] + bj;
    }
}

extern "C" void kernel_launch(void* const* d_in, const int* in_sizes, int n_in,
                              void* d_out, int out_size, void* d_ws, size_t ws_size,
                              hipStream_t stream) {
    const float* x      = (const float*)d_in[0];
    const float* th     = (const float*)d_in[1];
    const float* proj_w = (const float*)d_in[2];
    const float* proj_b = (const float*)d_in[3];
    const float* cf_w   = (const float*)d_in[4];
    const float* cf_b   = (const float*)d_in[5];
    const float* qw     = (const float*)d_in[6];
    const float* qb     = (const float*)d_in[7];
    const float* kw     = (const float*)d_in[8];
    const float* kb     = (const float*)d_in[9];
    const float* vw     = (const float*)d_in[10];
    const float* vb     = (const float*)d_in[11];
    const float* ow     = (const float*)d_in[12];
    const float* ob     = (const float*)d_in[13];
    const float* l1w    = (const float*)d_in[14];
    const float* l1b    = (const float*)d_in[15];
    const float* l2w    = (const float*)d_in[16];
    const float* l2b    = (const float*)d_in[17];
    const float* up_w   = (const float*)d_in[18];
    const float* up_b   = (const float*)d_in[19];
    const float* cl_w   = (const float*)d_in[20];
    const float* cl_b   = (const float*)d_in[21];

    float* ws   = (float*)d_ws;
    float* feat = ws;                         // 2,097,152 f
    float* tf   = feat + 2097152;             // 39,424 f
    unsigned short* k16 = (unsigned short*)(tf + 39424);   // 655,360 us
    unsigned short* vt16 = k16 + 655360;      // 786,432 us
    unsigned short* X1  = vt16 + 786432;      // 2,097,152 us
    unsigned short* X2  = X1 + 2097152;       // 8,388,608 us
    unsigned short* X3  = X2 + 8388608;       // 33,554,432 us
    unsigned short* PW1 = X3 + 33554432;      // 147,456 us
    unsigned short* PW2 = PW1 + 147456;       // 147,456 us
    unsigned short* PWF = PW2 + 147456;       // 9,216 us
    unsigned short* PQ  = PWF + 9216;         // 65,536 us
    unsigned short* PO  = PQ + 65536;         // 65,536 us

    hipLaunchKernelGGL(prep_kernel, dim3(8192 + 1152 + 36 + 256), dim3(256), 0, stream,
                       x, cf_w, cf_b, feat, up_w, PW1, PW2, cl_w, PWF, qw, ow, PQ, PO);
    hipLaunchKernelGGL(text_proj_kernel, dim3(BATCH * LTXT), dim3(64), 0, stream,
                       th, proj_w, proj_b, tf);
    hipLaunchKernelGGL(kv_all_kernel, dim3(16 * BATCH * 96), dim3(64), 0, stream,
                       tf, kw, kb, vw, vb, l2w, l2b, k16, vt16);

    hipLaunchKernelGGL(attn_all_kernel, dim3(BATCH * (HW0 / 64)), dim3(1024), 0, stream,
                       feat, k16, vt16, PQ, PO, qb, ob, l1w, l1b, X1);

    hipLaunchKernelGGL(upconv_mfma_kernel, dim3(BATCH * 64 * 64 / 64, 2), dim3(256), 0, stream,
                       X1, PW1, up_b, X2, 64, 64);
    hipLaunchKernelGGL(upconv_mfma_kernel, dim3(BATCH * 128 * 128 / 64, 2), dim3(256), 0, stream,
                       X2, PW2, up_b + 256, X3, 128, 128);
    hipLaunchKernelGGL(final_mfma_kernel, dim3(BATCH * 64 * 4), dim3(256), 0, stream,
                       X3, PWF, cl_b, (float*)d_out);
}